// Round 10
// baseline (179.400 us; speedup 1.0000x reference)
//
#include <hip/hip_runtime.h>

#define Nn 325
#define Dd 64
#define Hh 4
#define Ee 2600
#define BT 192
#define ETOT (Ee+Nn)        // 2925
#define NROWS (BT*Nn)       // 62400
#define XPS 68              // xpS row stride in shorts (136 B, bank-rotating)
#define NH0 163             // nodes in half 0 (half 1: 162)

#define XP_B (Nn * XPS * 2)            // 44200
#define EC_B (ETOT * 8)                // 23400
#define SMEM_BYTES (XP_B + EC_B + Nn*4 + Nn*4 + (Nn+1)*4)   // 71504

typedef __attribute__((ext_vector_type(8))) short bf16x8;
typedef __attribute__((ext_vector_type(4))) float f32x4;

static __device__ __forceinline__ short f2bf(float f) {
    union { float f; unsigned u; } v; v.f = f;
    unsigned r = v.u + 0x7fffu + ((v.u >> 16) & 1u);   // RNE (no NaN in data)
    return (short)(r >> 16);
}
static __device__ __forceinline__ float bf_lo(unsigned p) {
    union { unsigned u; float f; } v; v.u = p << 16; return v.f;
}
static __device__ __forceinline__ float bf_hi(unsigned p) {
    union { unsigned u; float f; } v; v.u = p & 0xffff0000u; return v.f;
}

// -- Kernel 0: Wt prearrange (blk 0..63) + CSR (blk 64) + x->bf16 (blk 65+) --
__global__ __launch_bounds__(256) void k_pre(
    const float* __restrict__ W, unsigned short* __restrict__ Wt,
    const int* __restrict__ ei, int* __restrict__ offs, int* __restrict__ elist,
    const float* __restrict__ x, unsigned short* __restrict__ xbf)
{
    const int t = threadIdx.x;
    if (blockIdx.x < 64) {
        const int f = blockIdx.x * 256 + t;             // 0..16383
        const int thr = f >> 6, idx = f & 63;
        const int ct = idx >> 4, kk = (idx >> 3) & 1, j = idx & 7;
        const int w = thr >> 6, lane = thr & 63;
        const int q = lane >> 4, l16 = lane & 15;
        Wt[f] = (unsigned short)f2bf(
            W[(size_t)(kk * 32 + q * 8 + j) * 256 + w * 64 + ct * 16 + l16]);
        return;
    }
    if (blockIdx.x >= 65) {
        const int bx = blockIdx.x - 65;
        #pragma unroll
        for (int k = 0; k < 8; ++k) {
            const int idx = bx * 2048 + k * 256 + t;
            if (idx < (NROWS * Dd) / 4) {
                float4 v = ((const float4*)x)[idx];
                ushort4 o;
                o.x = (unsigned short)f2bf(v.x);
                o.y = (unsigned short)f2bf(v.y);
                o.z = (unsigned short)f2bf(v.z);
                o.w = (unsigned short)f2bf(v.w);
                ((ushort4*)xbf)[idx] = o;
            }
        }
        return;
    }
    // ---- CSR build (plain node ids) ----
    __shared__ int cnt[Nn + 1];
    __shared__ int cur[Nn];
    const int lane = t & 63;
    for (int i = t; i <= Nn; i += 256) cnt[i] = 0;
    __syncthreads();
    for (int e = t; e < ETOT; e += 256) {
        int d = (e < Ee) ? ei[Ee + e] : (e - Ee);
        atomicAdd(&cnt[d + 1], 1);
    }
    __syncthreads();
    if (t < 64) {                       // wave-parallel inclusive scan
        int run = 0;
        for (int c = 0; c < 6; ++c) {
            int i = c * 64 + lane;
            int v = (i <= Nn) ? cnt[i] : 0;
            #pragma unroll
            for (int off = 1; off < 64; off <<= 1) {
                int u = __shfl_up(v, off);
                if (lane >= off) v += u;
            }
            v += run;
            if (i <= Nn) cnt[i] = v;
            run = __shfl(v, 63);
        }
    }
    __syncthreads();
    for (int i = t; i <= Nn; i += 256) offs[i] = cnt[i];
    for (int i = t; i < Nn; i += 256) cur[i] = cnt[i];
    __syncthreads();
    for (int e = t; e < ETOT; e += 256) {
        int s, d;
        if (e < Ee) { s = ei[e]; d = ei[Ee + e]; }
        else        { s = e - Ee; d = e - Ee; }
        int slot = atomicAdd(&cur[d], 1);
        elist[slot] = s;
    }
}

// ---- Kernel 1: fused GAT; block = (bt, node-half); 4 single-head phases ----
// 512 thr, 71.5 KB LDS -> 2 blocks/CU (independent barrier domains).
// Gather: (j,coef) packed int2 broadcast + row ds_read_b64 — no bpermute chain.
__global__ __launch_bounds__(512, 4) void k_fused(
    const unsigned short* __restrict__ xbf, const unsigned short* __restrict__ Wt,
    const float* __restrict__ x,
    const float* __restrict__ att_src, const float* __restrict__ att_dst,
    const int* __restrict__ offs, const int* __restrict__ elist,
    const float* __restrict__ bias, const float* __restrict__ gamma,
    const float* __restrict__ beta, float* __restrict__ out)
{
    const int bt   = blockIdx.x >> 1;
    const int hf   = blockIdx.x & 1;
    const int t    = threadIdx.x;     // 0..511
    const int wv   = t >> 6;          // 0..7
    const int lane = t & 63;
    const int q    = lane >> 4;
    const int l16  = lane & 15;
    const int btN  = bt * Nn;

    extern __shared__ char smem[];
    unsigned short* xpS   = (unsigned short*)smem;        // [Nn][XPS]
    int2*           ecS   = (int2*)(smem + XP_B);         // [ETOT] {j, coef-bits}
    float*          asrcS = (float*)(smem + XP_B + EC_B); // [Nn]
    float*          adstS = asrcS + Nn;                   // [Nn]
    int*            offsS = (int*)(adstS + Nn);           // [Nn+1]

    for (int i = t; i < ETOT; i += 512) ecS[i].x = elist[i];
    for (int i = t; i <= Nn; i += 512) offsS[i] = offs[i];

    const int nbase = hf ? NH0 : 0;
    const int ncnt  = hf ? (Nn - NH0) : NH0;
    const int g     = wv * 4 + q;     // 16-lane group id 0..31

    float accO[6][4];
    #pragma unroll
    for (int i = 0; i < 6; ++i)
        accO[i][0] = accO[i][1] = accO[i][2] = accO[i][3] = 0.f;

    #pragma unroll 1
    for (int p = 0; p < 4; ++p) {     // phase = head
        // B frags + attention vectors for head p (global, L1/L2-hot)
        bf16x8 bfr[4][2];
        const bf16x8* wtp = (const bf16x8*)(Wt + (size_t)(p * 64 + lane) * 64);
        #pragma unroll
        for (int ct = 0; ct < 4; ++ct) {
            bfr[ct][0] = wtp[ct * 2];
            bfr[ct][1] = wtp[ct * 2 + 1];
        }
        float avs[4], avd[4];
        #pragma unroll
        for (int ct = 0; ct < 4; ++ct) {
            avs[ct] = att_src[p * 64 + ct * 16 + l16];
            avd[ct] = att_dst[p * 64 + ct * 16 + l16];
        }
        if (p) __syncthreads();       // prev-phase gathers done before overwrite

        // ---- projection (all 325 nodes): tiles wv, wv+8, wv+16 ----
        #pragma unroll
        for (int k3 = 0; k3 < 3; ++k3) {
            const int rt = wv + 8 * k3;
            if (rt > 20) break;       // wave-uniform
            const int na = min(rt * 16 + l16, Nn - 1);
            bf16x8 afr[2];
            #pragma unroll
            for (int kk = 0; kk < 2; ++kk)
                afr[kk] = *(const bf16x8*)(xbf + (size_t)(btN + na) * 64 + kk * 32 + q * 8);
            f32x4 acc[4];
            #pragma unroll
            for (int ct = 0; ct < 4; ++ct) {
                acc[ct] = (f32x4){0.f, 0.f, 0.f, 0.f};
                acc[ct] = __builtin_amdgcn_mfma_f32_16x16x32_bf16(afr[0], bfr[ct][0], acc[ct], 0, 0, 0);
                acc[ct] = __builtin_amdgcn_mfma_f32_16x16x32_bf16(afr[1], bfr[ct][1], acc[ct], 0, 0, 0);
            }
            // C/D: col = l16 (tile ct), row = q*4 + r
            #pragma unroll
            for (int r = 0; r < 4; ++r) {
                const int n = rt * 16 + q * 4 + r;
                float ps = 0.f, pd = 0.f;
                #pragma unroll
                for (int ct = 0; ct < 4; ++ct) {
                    ps = fmaf(acc[ct][r], avs[ct], ps);
                    pd = fmaf(acc[ct][r], avd[ct], pd);
                }
                #pragma unroll
                for (int off = 1; off <= 8; off <<= 1) {
                    ps += __shfl_xor(ps, off);
                    pd += __shfl_xor(pd, off);
                }
                if (l16 == 0 && n < Nn) { asrcS[n] = ps; adstS[n] = pd; }
                if (n < Nn) {
                    #pragma unroll
                    for (int ct = 0; ct < 4; ++ct)
                        xpS[n * XPS + ct * 16 + l16] = (unsigned short)f2bf(acc[ct][r]);
                }
            }
        }
        __syncthreads();

        // ---- softmax + gather: group g owns nodes nbase + it*32 + g ----
        #pragma unroll 1
        for (int it = 0; it < 6; ++it) {
            const int idx = it * 32 + g;
            if (idx >= ncnt) break;   // group-uniform (exec-masked per quad)
            const int n = nbase + idx;
            const int o0 = offsS[n];
            int deg = offsS[n + 1] - o0;
            deg = min(deg, 48);
            const float adn = adstS[n];

            float ar[3];
            float m = -3e38f;
            #pragma unroll
            for (int rr = 0; rr < 3; ++rr) {
                if (rr * 16 >= deg) break;          // group-uniform
                const int e = rr * 16 + l16;
                float a = -3e38f;
                if (e < deg) {
                    const int j = ecS[o0 + e].x;    // contiguous b64 reads
                    a = asrcS[j] + adn;
                }
                a = (a >= 0.f) ? a : 0.2f * a;
                ar[rr] = a;
                m = fmaxf(m, a);
            }
            #pragma unroll
            for (int off = 1; off <= 8; off <<= 1) m = fmaxf(m, __shfl_xor(m, off));
            float s = 0.f;
            #pragma unroll
            for (int rr = 0; rr < 3; ++rr) {
                if (rr * 16 >= deg) break;
                ar[rr] = __expf(ar[rr] - m);
                s += ar[rr];
            }
            #pragma unroll
            for (int off = 1; off <= 8; off <<= 1) s += __shfl_xor(s, off);
            const float inv_s = 1.f / (s + 1e-16f);
            #pragma unroll
            for (int rr = 0; rr < 3; ++rr) {
                if (rr * 16 >= deg) break;
                const int e = rr * 16 + l16;
                if (e < deg) ecS[o0 + e].y = __float_as_int(ar[rr] * inv_s);
            }
            // same-wave write->read through LDS: per-wave DS ordering suffices

            float f0 = 0.f, f1 = 0.f, f2v = 0.f, f3 = 0.f;
            #pragma unroll 4
            for (int e2 = 0; e2 < deg; ++e2) {
                const int2 ec = ecS[o0 + e2];       // 16-lane broadcast b64
                const float c = __int_as_float(ec.y);
                const uint2 rw = *(const uint2*)((const char*)xpS +
                                     ec.x * (XPS * 2) + l16 * 8);
                f0  = fmaf(c, bf_lo(rw.x), f0);
                f1  = fmaf(c, bf_hi(rw.x), f1);
                f2v = fmaf(c, bf_lo(rw.y), f2v);
                f3  = fmaf(c, bf_hi(rw.y), f3);
            }
            accO[it][0] += f0; accO[it][1] += f1;
            accO[it][2] += f2v; accO[it][3] += f3;
        }
    }

    // ---- epilogue: head mean + bias + residual + LayerNorm ----
    const int f4 = l16 * 4;
    const float4 ga = *(const float4*)(gamma + f4);
    const float4 be = *(const float4*)(beta + f4);
    const float4 bi = *(const float4*)(bias + f4);
    #pragma unroll 1
    for (int it = 0; it < 6; ++it) {
        const int idx = it * 32 + g;
        if (idx >= ncnt) break;
        const int n = nbase + idx;
        const float4 xv = *(const float4*)(x + (size_t)(btN + n) * 64 + f4);
        const float y0 = xv.x + accO[it][0] * 0.25f + bi.x;
        const float y1 = xv.y + accO[it][1] * 0.25f + bi.y;
        const float y2 = xv.z + accO[it][2] * 0.25f + bi.z;
        const float y3 = xv.w + accO[it][3] * 0.25f + bi.w;
        float s1 = y0 + y1 + y2 + y3;
        float s2 = y0*y0 + y1*y1 + y2*y2 + y3*y3;
        #pragma unroll
        for (int off = 1; off <= 8; off <<= 1) {
            s1 += __shfl_xor(s1, off);
            s2 += __shfl_xor(s2, off);
        }
        const float mu  = s1 * (1.f / 64.f);
        const float var = s2 * (1.f / 64.f) - mu * mu;
        const float rr  = rsqrtf(var + 1e-5f);
        float4 o;
        o.x = (y0 - mu) * rr * ga.x + be.x;
        o.y = (y1 - mu) * rr * ga.y + be.y;
        o.z = (y2 - mu) * rr * ga.z + be.z;
        o.w = (y3 - mu) * rr * ga.w + be.w;
        *(float4*)(out + (size_t)(btN + n) * 64 + f4) = o;
    }
}

extern "C" void kernel_launch(void* const* d_in, const int* in_sizes, int n_in,
                              void* d_out, int out_size, void* d_ws, size_t ws_size,
                              hipStream_t stream)
{
    const float* x       = (const float*)d_in[0];
    const float* W       = (const float*)d_in[1];
    const float* att_src = (const float*)d_in[2];
    const float* att_dst = (const float*)d_in[3];
    const float* bias    = (const float*)d_in[4];
    const float* gamma   = (const float*)d_in[5];
    const float* beta    = (const float*)d_in[6];
    const int*   ei      = (const int*)d_in[7];

    unsigned short* Wt  = (unsigned short*)d_ws;           // 16384 bf16
    unsigned short* xbf = Wt + 16384;                      // NROWS*64 bf16
    int* offs  = (int*)(xbf + (size_t)NROWS * Dd);         // Nn+1
    int* elist = offs + (Nn + 1);                          // ETOT
    float* out = (float*)d_out;

    // opt-in to >64KB dynamic LDS (idempotent; capture-safe)
    hipFuncSetAttribute((const void*)k_fused,
                        hipFuncAttributeMaxDynamicSharedMemorySize, SMEM_BYTES);

    hipLaunchKernelGGL(k_pre, dim3(65 + 488), dim3(256), 0, stream,
                       W, Wt, ei, offs, elist, x, xbf);
    hipLaunchKernelGGL(k_fused, dim3(2 * BT), dim3(512), SMEM_BYTES, stream,
                       xbf, Wt, x, att_src, att_dst, offs, elist,
                       bias, gamma, beta, out);
}

// Round 11
// 139.420 us; speedup vs baseline: 1.2868x; 1.2868x over previous
//
#include <hip/hip_runtime.h>

#define Nn 325
#define Dd 64
#define Hh 4
#define Ee 2600
#define BT 192
#define ETOT (Ee+Nn)        // 2925
#define NROWS (BT*Nn)       // 62400
#define XPS 136             // xpS row stride in shorts (272 B)

#define XP_B   (Nn * XPS * 2)          // 88400
#define COEF_B (ETOT * 8)              // 23400
#define SMEM_BYTES (XP_B + COEF_B + 2600 + 2600 + ((Nn + 1) * 4) + (ETOT * 4)) // 130004

typedef __attribute__((ext_vector_type(8))) short bf16x8;
typedef __attribute__((ext_vector_type(4))) float f32x4;

static __device__ __forceinline__ short f2bf(float f) {
    union { float f; unsigned u; } v; v.f = f;
    unsigned r = v.u + 0x7fffu + ((v.u >> 16) & 1u);   // RNE (no NaN in data)
    return (short)(r >> 16);
}
static __device__ __forceinline__ float bf_lo(unsigned p) {
    union { unsigned u; float f; } v; v.u = p << 16; return v.f;
}
static __device__ __forceinline__ float bf_hi(unsigned p) {
    union { unsigned u; float f; } v; v.u = p & 0xffff0000u; return v.f;
}

// ---- Kernel 0: Wt prearrange (blocks 0..63) + CSR build (block 64) ----
__global__ __launch_bounds__(256) void k_pre(
    const float* __restrict__ W, unsigned short* __restrict__ Wt,
    const int* __restrict__ ei, int* __restrict__ offs, int* __restrict__ elist)
{
    const int t = threadIdx.x;
    if (blockIdx.x < 64) {
        const int f = blockIdx.x * 256 + t;             // 0..16383
        const int thr = f >> 6, idx = f & 63;
        const int ct = idx >> 4, kk = (idx >> 3) & 1, j = idx & 7;
        const int w = thr >> 6, lane = thr & 63;
        const int q = lane >> 4, l16 = lane & 15;
        Wt[f] = (unsigned short)f2bf(
            W[(size_t)(kk * 32 + q * 8 + j) * 256 + w * 64 + ct * 16 + l16]);
        return;
    }
    // ---- CSR build (plain node ids) ----
    __shared__ int cnt[Nn + 1];
    __shared__ int cur[Nn];
    const int lane = t & 63;
    for (int i = t; i <= Nn; i += 256) cnt[i] = 0;
    __syncthreads();
    for (int e = t; e < ETOT; e += 256) {
        int d = (e < Ee) ? ei[Ee + e] : (e - Ee);
        atomicAdd(&cnt[d + 1], 1);
    }
    __syncthreads();
    if (t < 64) {                       // wave-parallel inclusive scan
        int run = 0;
        for (int c = 0; c < 6; ++c) {
            int i = c * 64 + lane;
            int v = (i <= Nn) ? cnt[i] : 0;
            #pragma unroll
            for (int off = 1; off < 64; off <<= 1) {
                int u = __shfl_up(v, off);
                if (lane >= off) v += u;
            }
            v += run;
            if (i <= Nn) cnt[i] = v;
            run = __shfl(v, 63);
        }
    }
    __syncthreads();
    for (int i = t; i <= Nn; i += 256) offs[i] = cnt[i];
    for (int i = t; i < Nn; i += 256) cur[i] = cnt[i];
    __syncthreads();
    for (int e = t; e < ETOT; e += 256) {
        int s, d;
        if (e < Ee) { s = ei[e]; d = ei[Ee + e]; }
        else        { s = e - Ee; d = e - Ee; }
        int slot = atomicAdd(&cur[d], 1);
        elist[slot] = s;
    }
}

// --------- Kernel 1: fully fused per-bt GAT layer (one block = one bt) ---------
// R9 skeleton + LDS-staged per-edge coefs (no bpermute chain in the gather).
__global__ __launch_bounds__(1024, 4) void k_fused(
    const float* __restrict__ x, const unsigned short* __restrict__ Wt,
    const float* __restrict__ att_src, const float* __restrict__ att_dst,
    const int* __restrict__ offs, const int* __restrict__ elist,
    const float* __restrict__ bias, const float* __restrict__ gamma,
    const float* __restrict__ beta, float* __restrict__ out)
{
    const int bt   = blockIdx.x;
    const int t    = threadIdx.x;
    const int wv   = t >> 6;          // 0..15
    const int lane = t & 63;
    const int q    = lane >> 4;       // quad 0..3
    const int l16  = lane & 15;
    const int btN  = bt * Nn;

    extern __shared__ char smem[];
    unsigned short* xpS   = (unsigned short*)smem;              // [Nn][XPS]
    float2*         coefS = (float2*)(smem + XP_B);             // [ETOT]
    float*          asrcS = (float*)(smem + XP_B + COEF_B);     // [Nn][2]
    float*          adstS = asrcS + 2 * Nn;                     // [Nn][2]
    int*            offsS = (int*)(adstS + 2 * Nn);             // Nn+1
    int*            elistS= offsS + (Nn + 1);                   // ETOT

    for (int i = t; i < ETOT; i += 1024) elistS[i] = elist[i];
    for (int i = t; i <= Nn; i += 1024) offsS[i] = offs[i];

    float accO[6][4];
    #pragma unroll
    for (int i = 0; i < 6; ++i)
        accO[i][0] = accO[i][1] = accO[i][2] = accO[i][3] = 0.f;

    const int hh  = wv >> 3;          // head-half within phase (0/1)
    const int rtb = wv & 7;           // row-tile base

    #pragma unroll 2
    for (int p = 0; p < 2; ++p) {
        const int h = p * 2 + hh;     // global head
        bf16x8 bfr[4][2];
        const bf16x8* wtp = (const bf16x8*)(Wt + (size_t)(h * 64 + lane) * 64);
        #pragma unroll
        for (int ct = 0; ct < 4; ++ct) {
            bfr[ct][0] = wtp[ct * 2];
            bfr[ct][1] = wtp[ct * 2 + 1];
        }
        float avs[4], avd[4];
        #pragma unroll
        for (int ct = 0; ct < 4; ++ct) {
            avs[ct] = att_src[h * 64 + ct * 16 + l16];
            avd[ct] = att_dst[h * 64 + ct * 16 + l16];
        }
        if (p) __syncthreads();       // phase-1 writes wait for phase-0 reads

        // ---- projection: row-tiles rtb, rtb+8, rtb+16 (21 tiles total) ----
        #pragma unroll
        for (int k3 = 0; k3 < 3; ++k3) {
            const int rt = rtb + 8 * k3;
            if (rt > 20) break;       // wave-uniform
            bf16x8 afr[2];
            const int na = min(rt * 16 + l16, Nn - 1);
            const float* xr = x + (size_t)(btN + na) * 64 + q * 8;
            #pragma unroll
            for (int kk = 0; kk < 2; ++kk) {
                float4 v0 = *(const float4*)(xr + kk * 32);
                float4 v1 = *(const float4*)(xr + kk * 32 + 4);
                afr[kk][0]=f2bf(v0.x); afr[kk][1]=f2bf(v0.y);
                afr[kk][2]=f2bf(v0.z); afr[kk][3]=f2bf(v0.w);
                afr[kk][4]=f2bf(v1.x); afr[kk][5]=f2bf(v1.y);
                afr[kk][6]=f2bf(v1.z); afr[kk][7]=f2bf(v1.w);
            }
            f32x4 acc[4];
            #pragma unroll
            for (int ct = 0; ct < 4; ++ct) {
                acc[ct] = (f32x4){0.f, 0.f, 0.f, 0.f};
                acc[ct] = __builtin_amdgcn_mfma_f32_16x16x32_bf16(afr[0], bfr[ct][0], acc[ct], 0, 0, 0);
                acc[ct] = __builtin_amdgcn_mfma_f32_16x16x32_bf16(afr[1], bfr[ct][1], acc[ct], 0, 0, 0);
            }
            // C/D: col = l16 (tile ct), row = q*4 + r
            #pragma unroll
            for (int r = 0; r < 4; ++r) {
                const int n = rt * 16 + q * 4 + r;
                float ps = 0.f, pd = 0.f;
                #pragma unroll
                for (int ct = 0; ct < 4; ++ct) {
                    ps = fmaf(acc[ct][r], avs[ct], ps);
                    pd = fmaf(acc[ct][r], avd[ct], pd);
                }
                #pragma unroll
                for (int off = 1; off <= 8; off <<= 1) {
                    ps += __shfl_xor(ps, off);
                    pd += __shfl_xor(pd, off);
                }
                if (l16 == 0 && n < Nn) {
                    asrcS[n * 2 + hh] = ps;
                    adstS[n * 2 + hh] = pd;
                }
                if (n < Nn) {
                    #pragma unroll
                    for (int ct = 0; ct < 4; ++ct)
                        xpS[n * XPS + (ct * 16 + l16) * 2 + hh] =
                            (unsigned short)f2bf(acc[ct][r]);
                }
            }
        }
        __syncthreads();

        // ---- softmax + gather: 16-lane group (wv,q) owns nodes wv*4+q+it*64 ----
        #pragma unroll
        for (int it = 0; it < 6; ++it) {
            const int n = wv * 4 + q + it * 64;
            if (n >= Nn) break;
            const int o0 = offsS[n];
            int deg = offsS[n + 1] - o0;
            deg = min(deg, 48);
            const float adn0 = adstS[n * 2], adn1 = adstS[n * 2 + 1];
            float ex0[3], ex1[3];
            float m0 = -3e38f, m1 = -3e38f;
            #pragma unroll
            for (int r = 0; r < 3; ++r) {
                float a0 = -3e38f, a1 = -3e38f;
                if (r * 16 < deg) {
                    const int e = r * 16 + l16;
                    if (e < deg) {
                        const int j = elistS[o0 + e];
                        const float2 as = *(const float2*)(asrcS + j * 2);
                        a0 = as.x + adn0; a1 = as.y + adn1;
                    }
                }
                a0 = (a0 >= 0.f) ? a0 : 0.2f * a0;
                a1 = (a1 >= 0.f) ? a1 : 0.2f * a1;
                ex0[r] = a0; ex1[r] = a1;
                m0 = fmaxf(m0, a0); m1 = fmaxf(m1, a1);
            }
            #pragma unroll
            for (int off = 1; off <= 8; off <<= 1) {
                m0 = fmaxf(m0, __shfl_xor(m0, off));
                m1 = fmaxf(m1, __shfl_xor(m1, off));
            }
            float s0 = 0.f, s1 = 0.f;
            #pragma unroll
            for (int r = 0; r < 3; ++r) if (r * 16 < deg) {
                ex0[r] = __expf(ex0[r] - m0); s0 += ex0[r];
                ex1[r] = __expf(ex1[r] - m1); s1 += ex1[r];
            }
            #pragma unroll
            for (int off = 1; off <= 8; off <<= 1) {
                s0 += __shfl_xor(s0, off);
                s1 += __shfl_xor(s1, off);
            }
            const float i0 = 1.f / (s0 + 1e-16f);
            const float i1 = 1.f / (s1 + 1e-16f);
            // stage normalized coefs per edge (read back by same wave)
            #pragma unroll
            for (int r = 0; r < 3; ++r) if (r * 16 < deg) {
                const int e = r * 16 + l16;
                if (e < deg) coefS[o0 + e] = make_float2(ex0[r] * i0, ex1[r] * i1);
            }

            // gather: per edge = b32 j-broadcast + b64 coef-broadcast + b128 row
            float f0 = 0.f, f1 = 0.f, f2v = 0.f, f3 = 0.f;
            int e2 = 0;
            for (; e2 + 2 <= deg; e2 += 2) {
                const int ja = elistS[o0 + e2];
                const int jb = elistS[o0 + e2 + 1];
                const float2 ca = coefS[o0 + e2];
                const float2 cb = coefS[o0 + e2 + 1];
                const uint4 ra = *(const uint4*)((const char*)xpS + ja * (XPS * 2) + l16 * 16);
                const uint4 rb = *(const uint4*)((const char*)xpS + jb * (XPS * 2) + l16 * 16);
                f0  = fmaf(ca.x, bf_lo(ra.x), f0);  f0  = fmaf(ca.y, bf_hi(ra.x), f0);
                f1  = fmaf(ca.x, bf_lo(ra.y), f1);  f1  = fmaf(ca.y, bf_hi(ra.y), f1);
                f2v = fmaf(ca.x, bf_lo(ra.z), f2v); f2v = fmaf(ca.y, bf_hi(ra.z), f2v);
                f3  = fmaf(ca.x, bf_lo(ra.w), f3);  f3  = fmaf(ca.y, bf_hi(ra.w), f3);
                f0  = fmaf(cb.x, bf_lo(rb.x), f0);  f0  = fmaf(cb.y, bf_hi(rb.x), f0);
                f1  = fmaf(cb.x, bf_lo(rb.y), f1);  f1  = fmaf(cb.y, bf_hi(rb.y), f1);
                f2v = fmaf(cb.x, bf_lo(rb.z), f2v); f2v = fmaf(cb.y, bf_hi(rb.z), f2v);
                f3  = fmaf(cb.x, bf_lo(rb.w), f3);  f3  = fmaf(cb.y, bf_hi(rb.w), f3);
            }
            if (e2 < deg) {
                const int ja = elistS[o0 + e2];
                const float2 ca = coefS[o0 + e2];
                const uint4 ra = *(const uint4*)((const char*)xpS + ja * (XPS * 2) + l16 * 16);
                f0  = fmaf(ca.x, bf_lo(ra.x), f0);  f0  = fmaf(ca.y, bf_hi(ra.x), f0);
                f1  = fmaf(ca.x, bf_lo(ra.y), f1);  f1  = fmaf(ca.y, bf_hi(ra.y), f1);
                f2v = fmaf(ca.x, bf_lo(ra.z), f2v); f2v = fmaf(ca.y, bf_hi(ra.z), f2v);
                f3  = fmaf(ca.x, bf_lo(ra.w), f3);  f3  = fmaf(ca.y, bf_hi(ra.w), f3);
            }
            accO[it][0] += f0; accO[it][1] += f1;
            accO[it][2] += f2v; accO[it][3] += f3;
        }
    }

    // ---- epilogue: head mean + bias + residual + LayerNorm ----
    const int f4 = l16 * 4;
    const float4 ga = *(const float4*)(gamma + f4);
    const float4 be = *(const float4*)(beta + f4);
    const float4 bi = *(const float4*)(bias + f4);
    #pragma unroll
    for (int it = 0; it < 6; ++it) {
        const int n = wv * 4 + q + it * 64;
        if (n >= Nn) break;
        const float4 xv = *(const float4*)(x + (size_t)(btN + n) * 64 + f4);
        const float y0 = xv.x + accO[it][0] * 0.25f + bi.x;
        const float y1 = xv.y + accO[it][1] * 0.25f + bi.y;
        const float y2 = xv.z + accO[it][2] * 0.25f + bi.z;
        const float y3 = xv.w + accO[it][3] * 0.25f + bi.w;
        float s1 = y0 + y1 + y2 + y3;
        float s2 = y0*y0 + y1*y1 + y2*y2 + y3*y3;
        #pragma unroll
        for (int off = 1; off <= 8; off <<= 1) {
            s1 += __shfl_xor(s1, off);
            s2 += __shfl_xor(s2, off);
        }
        const float mu  = s1 * (1.f / 64.f);
        const float var = s2 * (1.f / 64.f) - mu * mu;
        const float rr  = rsqrtf(var + 1e-5f);
        float4 o;
        o.x = (y0 - mu) * rr * ga.x + be.x;
        o.y = (y1 - mu) * rr * ga.y + be.y;
        o.z = (y2 - mu) * rr * ga.z + be.z;
        o.w = (y3 - mu) * rr * ga.w + be.w;
        *(float4*)(out + (size_t)(btN + n) * 64 + f4) = o;
    }
}

extern "C" void kernel_launch(void* const* d_in, const int* in_sizes, int n_in,
                              void* d_out, int out_size, void* d_ws, size_t ws_size,
                              hipStream_t stream)
{
    const float* x       = (const float*)d_in[0];
    const float* W       = (const float*)d_in[1];
    const float* att_src = (const float*)d_in[2];
    const float* att_dst = (const float*)d_in[3];
    const float* bias    = (const float*)d_in[4];
    const float* gamma   = (const float*)d_in[5];
    const float* beta    = (const float*)d_in[6];
    const int*   ei      = (const int*)d_in[7];

    unsigned short* Wt = (unsigned short*)d_ws;            // 16384 bf16
    int* offs  = (int*)(Wt + 16384);                       // Nn+1
    int* elist = offs + (Nn + 1);                          // ETOT
    float* out = (float*)d_out;

    // opt-in to >64KB dynamic LDS (idempotent; capture-safe)
    hipFuncSetAttribute((const void*)k_fused,
                        hipFuncAttributeMaxDynamicSharedMemorySize, SMEM_BYTES);

    hipLaunchKernelGGL(k_pre, dim3(65), dim3(256), 0, stream,
                       W, Wt, ei, offs, elist);
    hipLaunchKernelGGL(k_fused, dim3(BT), dim3(1024), SMEM_BYTES, stream,
                       x, Wt, att_src, att_dst, offs, elist,
                       bias, gamma, beta, out);
}

// Round 12
// 134.187 us; speedup vs baseline: 1.3369x; 1.0390x over previous
//
#include <hip/hip_runtime.h>

#define Nn 325
#define Dd 64
#define Hh 4
#define Ee 2600
#define BT 192
#define ETOT (Ee+Nn)        // 2925
#define NROWS (BT*Nn)       // 62400
#define XPS 136             // xpS row stride in shorts (272 B)

#define XP_B   (Nn * XPS * 2)          // 88400
#define COEF_B (ETOT * 8)              // 23400
#define SMEM_BYTES (XP_B + COEF_B + 2600 + 2600 + ((Nn + 1) * 4) + (ETOT * 4) + (Nn * 4))

typedef __attribute__((ext_vector_type(8))) short bf16x8;
typedef __attribute__((ext_vector_type(4))) float f32x4;

static __device__ __forceinline__ short f2bf(float f) {
    union { float f; unsigned u; } v; v.f = f;
    unsigned r = v.u + 0x7fffu + ((v.u >> 16) & 1u);   // RNE (no NaN in data)
    return (short)(r >> 16);
}
static __device__ __forceinline__ float bf_lo(unsigned p) {
    union { unsigned u; float f; } v; v.u = p << 16; return v.f;
}
static __device__ __forceinline__ float bf_hi(unsigned p) {
    union { unsigned u; float f; } v; v.u = p & 0xffff0000u; return v.f;
}

// -- Kernel 0: Wt prearrange (blk 0..63) + CSR/deg-sort (blk 64) + x->bf16 --
__global__ __launch_bounds__(256) void k_pre(
    const float* __restrict__ W, unsigned short* __restrict__ Wt,
    const int* __restrict__ ei, int* __restrict__ offs, int* __restrict__ elist,
    int* __restrict__ perm, const float* __restrict__ x,
    unsigned short* __restrict__ xbf)
{
    const int t = threadIdx.x;
    if (blockIdx.x < 64) {
        const int f = blockIdx.x * 256 + t;             // 0..16383
        const int thr = f >> 6, idx = f & 63;
        const int ct = idx >> 4, kk = (idx >> 3) & 1, j = idx & 7;
        const int w = thr >> 6, lane = thr & 63;
        const int q = lane >> 4, l16 = lane & 15;
        Wt[f] = (unsigned short)f2bf(
            W[(size_t)(kk * 32 + q * 8 + j) * 256 + w * 64 + ct * 16 + l16]);
        return;
    }
    if (blockIdx.x >= 65) {
        // x (fp32) -> xbf (bf16)
        const int bx = blockIdx.x - 65;
        #pragma unroll
        for (int k = 0; k < 8; ++k) {
            const int idx = bx * 2048 + k * 256 + t;
            if (idx < (NROWS * Dd) / 4) {
                float4 v = ((const float4*)x)[idx];
                ushort4 o;
                o.x = (unsigned short)f2bf(v.x);
                o.y = (unsigned short)f2bf(v.y);
                o.z = (unsigned short)f2bf(v.z);
                o.w = (unsigned short)f2bf(v.w);
                ((ushort4*)xbf)[idx] = o;
            }
        }
        return;
    }
    // ---- CSR build + degree-descending counting sort (block 64) ----
    __shared__ int cnt[Nn + 1];
    __shared__ int cur[Nn];
    __shared__ int dh[64];
    __shared__ int startS[64];
    const int lane = t & 63;
    for (int i = t; i <= Nn; i += 256) cnt[i] = 0;
    if (t < 64) dh[t] = 0;
    __syncthreads();
    for (int e = t; e < ETOT; e += 256) {
        int d = (e < Ee) ? ei[Ee + e] : (e - Ee);
        atomicAdd(&cnt[d + 1], 1);
    }
    __syncthreads();
    if (t < 64) {                       // wave-parallel inclusive scan
        int run = 0;
        for (int c = 0; c < 6; ++c) {
            int i = c * 64 + lane;
            int v = (i <= Nn) ? cnt[i] : 0;
            #pragma unroll
            for (int off = 1; off < 64; off <<= 1) {
                int u = __shfl_up(v, off);
                if (lane >= off) v += u;
            }
            v += run;
            if (i <= Nn) cnt[i] = v;
            run = __shfl(v, 63);
        }
    }
    __syncthreads();
    for (int i = t; i <= Nn; i += 256) offs[i] = cnt[i];
    for (int i = t; i < Nn; i += 256) cur[i] = cnt[i];
    // degree histogram (clamped to 63)
    for (int n = t; n < Nn; n += 256)
        atomicAdd(&dh[min(cnt[n + 1] - cnt[n], 63)], 1);
    __syncthreads();
    if (t < 64) {                       // descending: start[d] = #nodes with deg > d
        int v = dh[63 - lane];
        int inc = v;
        #pragma unroll
        for (int off = 1; off < 64; off <<= 1) {
            int u = __shfl_up(inc, off);
            if (lane >= off) inc += u;
        }
        startS[63 - lane] = inc - v;
    }
    __syncthreads();
    for (int e = t; e < ETOT; e += 256) {
        int s, d;
        if (e < Ee) { s = ei[e]; d = ei[Ee + e]; }
        else        { s = e - Ee; d = e - Ee; }
        int slot = atomicAdd(&cur[d], 1);
        elist[slot] = s;
    }
    for (int n = t; n < Nn; n += 256) {
        int slot = atomicAdd(&startS[min(cnt[n + 1] - cnt[n], 63)], 1);
        perm[slot] = n;
    }
}

// --------- Kernel 1: fully fused per-bt GAT layer (one block = one bt) ---------
// R11 skeleton + degree-balanced perm assignment + 4-edge ILP gather + xbf.
__global__ __launch_bounds__(1024, 4) void k_fused(
    const float* __restrict__ x, const unsigned short* __restrict__ xbf,
    const unsigned short* __restrict__ Wt,
    const float* __restrict__ att_src, const float* __restrict__ att_dst,
    const int* __restrict__ offs, const int* __restrict__ elist,
    const int* __restrict__ perm,
    const float* __restrict__ bias, const float* __restrict__ gamma,
    const float* __restrict__ beta, float* __restrict__ out)
{
    const int bt   = blockIdx.x;
    const int t    = threadIdx.x;
    const int wv   = t >> 6;          // 0..15
    const int lane = t & 63;
    const int q    = lane >> 4;       // quad 0..3
    const int l16  = lane & 15;
    const int btN  = bt * Nn;

    extern __shared__ char smem[];
    unsigned short* xpS   = (unsigned short*)smem;              // [Nn][XPS]
    float2*         coefS = (float2*)(smem + XP_B);             // [ETOT]
    float*          asrcS = (float*)(smem + XP_B + COEF_B);     // [Nn][2]
    float*          adstS = asrcS + 2 * Nn;                     // [Nn][2]
    int*            offsS = (int*)(adstS + 2 * Nn);             // Nn+1
    int*            elistS= offsS + (Nn + 1);                   // ETOT
    int*            permS = elistS + ETOT;                      // Nn

    for (int i = t; i < ETOT; i += 1024) elistS[i] = elist[i];
    for (int i = t; i <= Nn; i += 1024) offsS[i] = offs[i];
    for (int i = t; i < Nn; i += 1024) permS[i] = perm[i];

    float accO[6][4];
    #pragma unroll
    for (int i = 0; i < 6; ++i)
        accO[i][0] = accO[i][1] = accO[i][2] = accO[i][3] = 0.f;

    const int hh  = wv >> 3;          // head-half within phase (0/1)
    const int rtb = wv & 7;           // row-tile base
    const int g   = wv * 4 + q;       // 16-lane group id 0..63

    #pragma unroll 2
    for (int p = 0; p < 2; ++p) {
        const int h = p * 2 + hh;     // global head
        bf16x8 bfr[4][2];
        const bf16x8* wtp = (const bf16x8*)(Wt + (size_t)(h * 64 + lane) * 64);
        #pragma unroll
        for (int ct = 0; ct < 4; ++ct) {
            bfr[ct][0] = wtp[ct * 2];
            bfr[ct][1] = wtp[ct * 2 + 1];
        }
        float avs[4], avd[4];
        #pragma unroll
        for (int ct = 0; ct < 4; ++ct) {
            avs[ct] = att_src[h * 64 + ct * 16 + l16];
            avd[ct] = att_dst[h * 64 + ct * 16 + l16];
        }
        if (p) __syncthreads();       // phase-1 writes wait for phase-0 reads

        // ---- projection: row-tiles rtb, rtb+8, rtb+16 (21 tiles total) ----
        #pragma unroll
        for (int k3 = 0; k3 < 3; ++k3) {
            const int rt = rtb + 8 * k3;
            if (rt > 20) break;       // wave-uniform
            const int na = min(rt * 16 + l16, Nn - 1);
            bf16x8 afr[2];
            #pragma unroll
            for (int kk = 0; kk < 2; ++kk)
                afr[kk] = *(const bf16x8*)(xbf + (size_t)(btN + na) * 64 + kk * 32 + q * 8);
            f32x4 acc[4];
            #pragma unroll
            for (int ct = 0; ct < 4; ++ct) {
                acc[ct] = (f32x4){0.f, 0.f, 0.f, 0.f};
                acc[ct] = __builtin_amdgcn_mfma_f32_16x16x32_bf16(afr[0], bfr[ct][0], acc[ct], 0, 0, 0);
                acc[ct] = __builtin_amdgcn_mfma_f32_16x16x32_bf16(afr[1], bfr[ct][1], acc[ct], 0, 0, 0);
            }
            // C/D: col = l16 (tile ct), row = q*4 + r
            #pragma unroll
            for (int r = 0; r < 4; ++r) {
                const int n = rt * 16 + q * 4 + r;
                float ps = 0.f, pd = 0.f;
                #pragma unroll
                for (int ct = 0; ct < 4; ++ct) {
                    ps = fmaf(acc[ct][r], avs[ct], ps);
                    pd = fmaf(acc[ct][r], avd[ct], pd);
                }
                #pragma unroll
                for (int off = 1; off <= 8; off <<= 1) {
                    ps += __shfl_xor(ps, off);
                    pd += __shfl_xor(pd, off);
                }
                if (l16 == 0 && n < Nn) {
                    asrcS[n * 2 + hh] = ps;
                    adstS[n * 2 + hh] = pd;
                }
                if (n < Nn) {
                    #pragma unroll
                    for (int ct = 0; ct < 4; ++ct)
                        xpS[n * XPS + (ct * 16 + l16) * 2 + hh] =
                            (unsigned short)f2bf(acc[ct][r]);
                }
            }
        }
        __syncthreads();

        // ---- softmax + gather: group g handles sorted-ranks it*64+g ----
        #pragma unroll
        for (int it = 0; it < 6; ++it) {
            const int rk = it * 64 + g;
            if (rk >= Nn) continue;   // exec-masked per group (boundary wave only)
            const int n = permS[rk];
            const int o0 = offsS[n];
            int deg = offsS[n + 1] - o0;
            deg = min(deg, 48);
            const float adn0 = adstS[n * 2], adn1 = adstS[n * 2 + 1];
            float ex0[3], ex1[3];
            float m0 = -3e38f, m1 = -3e38f;
            #pragma unroll
            for (int r = 0; r < 3; ++r) {
                float a0 = -3e38f, a1 = -3e38f;
                if (r * 16 < deg) {
                    const int e = r * 16 + l16;
                    if (e < deg) {
                        const int j = elistS[o0 + e];
                        const float2 as = *(const float2*)(asrcS + j * 2);
                        a0 = as.x + adn0; a1 = as.y + adn1;
                    }
                }
                a0 = (a0 >= 0.f) ? a0 : 0.2f * a0;
                a1 = (a1 >= 0.f) ? a1 : 0.2f * a1;
                ex0[r] = a0; ex1[r] = a1;
                m0 = fmaxf(m0, a0); m1 = fmaxf(m1, a1);
            }
            #pragma unroll
            for (int off = 1; off <= 8; off <<= 1) {
                m0 = fmaxf(m0, __shfl_xor(m0, off));
                m1 = fmaxf(m1, __shfl_xor(m1, off));
            }
            float s0 = 0.f, s1 = 0.f;
            #pragma unroll
            for (int r = 0; r < 3; ++r) if (r * 16 < deg) {
                ex0[r] = __expf(ex0[r] - m0); s0 += ex0[r];
                ex1[r] = __expf(ex1[r] - m1); s1 += ex1[r];
            }
            #pragma unroll
            for (int off = 1; off <= 8; off <<= 1) {
                s0 += __shfl_xor(s0, off);
                s1 += __shfl_xor(s1, off);
            }
            const float i0 = 1.f / (s0 + 1e-16f);
            const float i1 = 1.f / (s1 + 1e-16f);
            #pragma unroll
            for (int r = 0; r < 3; ++r) if (r * 16 < deg) {
                const int e = r * 16 + l16;
                if (e < deg) coefS[o0 + e] = make_float2(ex0[r] * i0, ex1[r] * i1);
            }
            // same-wave write->read through LDS: per-wave DS ordering suffices

            // gather: 4-edge unrolled (4 independent b128 rows in flight)
            float f0 = 0.f, f1 = 0.f, f2v = 0.f, f3 = 0.f;
            int e2 = 0;
            for (; e2 + 4 <= deg; e2 += 4) {
                const int j0 = elistS[o0 + e2],     j1 = elistS[o0 + e2 + 1];
                const int j2 = elistS[o0 + e2 + 2], j3 = elistS[o0 + e2 + 3];
                const float2 c0 = coefS[o0 + e2],     c1 = coefS[o0 + e2 + 1];
                const float2 c2 = coefS[o0 + e2 + 2], c3 = coefS[o0 + e2 + 3];
                const uint4 r0 = *(const uint4*)((const char*)xpS + j0 * (XPS * 2) + l16 * 16);
                const uint4 r1 = *(const uint4*)((const char*)xpS + j1 * (XPS * 2) + l16 * 16);
                const uint4 r2 = *(const uint4*)((const char*)xpS + j2 * (XPS * 2) + l16 * 16);
                const uint4 r3 = *(const uint4*)((const char*)xpS + j3 * (XPS * 2) + l16 * 16);
                f0  = fmaf(c0.x, bf_lo(r0.x), f0);  f0  = fmaf(c0.y, bf_hi(r0.x), f0);
                f1  = fmaf(c0.x, bf_lo(r0.y), f1);  f1  = fmaf(c0.y, bf_hi(r0.y), f1);
                f2v = fmaf(c0.x, bf_lo(r0.z), f2v); f2v = fmaf(c0.y, bf_hi(r0.z), f2v);
                f3  = fmaf(c0.x, bf_lo(r0.w), f3);  f3  = fmaf(c0.y, bf_hi(r0.w), f3);
                f0  = fmaf(c1.x, bf_lo(r1.x), f0);  f0  = fmaf(c1.y, bf_hi(r1.x), f0);
                f1  = fmaf(c1.x, bf_lo(r1.y), f1);  f1  = fmaf(c1.y, bf_hi(r1.y), f1);
                f2v = fmaf(c1.x, bf_lo(r1.z), f2v); f2v = fmaf(c1.y, bf_hi(r1.z), f2v);
                f3  = fmaf(c1.x, bf_lo(r1.w), f3);  f3  = fmaf(c1.y, bf_hi(r1.w), f3);
                f0  = fmaf(c2.x, bf_lo(r2.x), f0);  f0  = fmaf(c2.y, bf_hi(r2.x), f0);
                f1  = fmaf(c2.x, bf_lo(r2.y), f1);  f1  = fmaf(c2.y, bf_hi(r2.y), f1);
                f2v = fmaf(c2.x, bf_lo(r2.z), f2v); f2v = fmaf(c2.y, bf_hi(r2.z), f2v);
                f3  = fmaf(c2.x, bf_lo(r2.w), f3);  f3  = fmaf(c2.y, bf_hi(r2.w), f3);
                f0  = fmaf(c3.x, bf_lo(r3.x), f0);  f0  = fmaf(c3.y, bf_hi(r3.x), f0);
                f1  = fmaf(c3.x, bf_lo(r3.y), f1);  f1  = fmaf(c3.y, bf_hi(r3.y), f1);
                f2v = fmaf(c3.x, bf_lo(r3.z), f2v); f2v = fmaf(c3.y, bf_hi(r3.z), f2v);
                f3  = fmaf(c3.x, bf_lo(r3.w), f3);  f3  = fmaf(c3.y, bf_hi(r3.w), f3);
            }
            for (; e2 < deg; ++e2) {
                const int ja = elistS[o0 + e2];
                const float2 ca = coefS[o0 + e2];
                const uint4 ra = *(const uint4*)((const char*)xpS + ja * (XPS * 2) + l16 * 16);
                f0  = fmaf(ca.x, bf_lo(ra.x), f0);  f0  = fmaf(ca.y, bf_hi(ra.x), f0);
                f1  = fmaf(ca.x, bf_lo(ra.y), f1);  f1  = fmaf(ca.y, bf_hi(ra.y), f1);
                f2v = fmaf(ca.x, bf_lo(ra.z), f2v); f2v = fmaf(ca.y, bf_hi(ra.z), f2v);
                f3  = fmaf(ca.x, bf_lo(ra.w), f3);  f3  = fmaf(ca.y, bf_hi(ra.w), f3);
            }
            accO[it][0] += f0; accO[it][1] += f1;
            accO[it][2] += f2v; accO[it][3] += f3;
        }
    }

    // ---- epilogue: head mean + bias + residual + LayerNorm ----
    const int f4 = l16 * 4;
    const float4 ga = *(const float4*)(gamma + f4);
    const float4 be = *(const float4*)(beta + f4);
    const float4 bi = *(const float4*)(bias + f4);
    #pragma unroll
    for (int it = 0; it < 6; ++it) {
        const int rk = it * 64 + g;
        if (rk >= Nn) continue;       // exec-masked per group
        const int n = permS[rk];
        const float4 xv = *(const float4*)(x + (size_t)(btN + n) * 64 + f4);
        const float y0 = xv.x + accO[it][0] * 0.25f + bi.x;
        const float y1 = xv.y + accO[it][1] * 0.25f + bi.y;
        const float y2 = xv.z + accO[it][2] * 0.25f + bi.z;
        const float y3 = xv.w + accO[it][3] * 0.25f + bi.w;
        float s1 = y0 + y1 + y2 + y3;
        float s2 = y0*y0 + y1*y1 + y2*y2 + y3*y3;
        #pragma unroll
        for (int off = 1; off <= 8; off <<= 1) {
            s1 += __shfl_xor(s1, off);
            s2 += __shfl_xor(s2, off);
        }
        const float mu  = s1 * (1.f / 64.f);
        const float var = s2 * (1.f / 64.f) - mu * mu;
        const float rr  = rsqrtf(var + 1e-5f);
        float4 o;
        o.x = (y0 - mu) * rr * ga.x + be.x;
        o.y = (y1 - mu) * rr * ga.y + be.y;
        o.z = (y2 - mu) * rr * ga.z + be.z;
        o.w = (y3 - mu) * rr * ga.w + be.w;
        *(float4*)(out + (size_t)(btN + n) * 64 + f4) = o;
    }
}

extern "C" void kernel_launch(void* const* d_in, const int* in_sizes, int n_in,
                              void* d_out, int out_size, void* d_ws, size_t ws_size,
                              hipStream_t stream)
{
    const float* x       = (const float*)d_in[0];
    const float* W       = (const float*)d_in[1];
    const float* att_src = (const float*)d_in[2];
    const float* att_dst = (const float*)d_in[3];
    const float* bias    = (const float*)d_in[4];
    const float* gamma   = (const float*)d_in[5];
    const float* beta    = (const float*)d_in[6];
    const int*   ei      = (const int*)d_in[7];

    unsigned short* Wt  = (unsigned short*)d_ws;           // 16384 bf16
    unsigned short* xbf = Wt + 16384;                      // NROWS*64 bf16
    int* offs  = (int*)(xbf + (size_t)NROWS * Dd);         // Nn+1
    int* elist = offs + (Nn + 1);                          // ETOT
    int* perm  = elist + ETOT;                             // Nn
    float* out = (float*)d_out;

    // opt-in to >64KB dynamic LDS (idempotent; capture-safe)
    hipFuncSetAttribute((const void*)k_fused,
                        hipFuncAttributeMaxDynamicSharedMemorySize, SMEM_BYTES);

    hipLaunchKernelGGL(k_pre, dim3(65 + 488), dim3(256), 0, stream,
                       W, Wt, ei, offs, elist, perm, x, xbf);
    hipLaunchKernelGGL(k_fused, dim3(BT), dim3(1024), SMEM_BYTES, stream,
                       x, xbf, Wt, att_src, att_dst, offs, elist, perm,
                       bias, gamma, beta, out);
}